// Round 2
// baseline (980.941 us; speedup 1.0000x reference)
//
#include <hip/hip_runtime.h>
#include <stdint.h>
#include <stddef.h>

#define TOK 8192
#define H 1024
#define IDIM 2048
#define NE 32
#define BM 128
#define BN 64
#define BK 64
#define MAX_TILES 96

typedef __attribute__((ext_vector_type(8))) short short8;
typedef __attribute__((ext_vector_type(4))) float f32x4;
typedef __attribute__((ext_vector_type(4))) float float4v;
typedef __attribute__((ext_vector_type(2))) unsigned int uint2v;

// ---- helpers -------------------------------------------------------------

__device__ __forceinline__ unsigned short f2bf(float x) {   // RNE fp32->bf16
  unsigned u = __builtin_bit_cast(unsigned, x);
  u += 0x7fffu + ((u >> 16) & 1u);
  return (unsigned short)(u >> 16);
}

// async global->LDS, 16B per lane; LDS dest = wave-uniform base + lane*16
__device__ __forceinline__ void gll16(const void* g, void* l) {
  __builtin_amdgcn_global_load_lds(
      (const __attribute__((address_space(1))) unsigned int*)g,
      (__attribute__((address_space(3))) unsigned int*)l, 16, 0, 0);
}

__device__ __forceinline__ f32x4 mfma16(short8 a, short8 b, f32x4 c) {
  return __builtin_amdgcn_mfma_f32_16x16x32_bf16(a, b, c, 0, 0, 0);
}

// ---- 1) router: logits, top-1, sigmoid, bf16 casts ----------------------

__global__ __launch_bounds__(256) void router_kernel(
    const float* __restrict__ x, const float* __restrict__ gw,
    unsigned short* __restrict__ xbf, unsigned short* __restrict__ xsbf,
    int* __restrict__ expert_id, int* __restrict__ counts)
{
  __shared__ float xl[8 * H];          // 8 token rows, 32KB
  __shared__ float plog[8][8][NE];     // [chunk][tok][e]
  __shared__ float sscore[8];
  const int tid = threadIdx.x;
  const long t0 = (long)blockIdx.x * 8;

  const float4v* src = (const float4v*)(x + t0 * H);
  float4v* dst = (float4v*)xl;
  #pragma unroll
  for (int i = 0; i < 8; ++i) dst[tid + i * 256] = src[tid + i * 256];
  __syncthreads();

  {
    const int e = tid & 31, c = tid >> 5;
    float acc[8] = {0, 0, 0, 0, 0, 0, 0, 0};
    const float* gp = gw + (c * 128) * NE + e;
    for (int h = 0; h < 128; ++h) {
      float g = gp[h * NE];
      const float* xr = xl + (c * 128 + h);
      #pragma unroll
      for (int tk = 0; tk < 8; ++tk) acc[tk] += xr[tk * H] * g;
    }
    #pragma unroll
    for (int tk = 0; tk < 8; ++tk) plog[c][tk][e] = acc[tk];
  }
  __syncthreads();
  {
    const int e = tid & 31, tok = tid >> 5;
    float lg = 0.f;
    #pragma unroll
    for (int c = 0; c < 8; ++c) lg += plog[c][tok][e];
    float m = lg; int be = e;
    #pragma unroll
    for (int mask = 16; mask >= 1; mask >>= 1) {   // reduce within 32-lane group
      float om = __shfl_xor(m, mask);
      int   oe = __shfl_xor(be, mask);
      if (om > m || (om == m && oe < be)) { m = om; be = oe; }  // first-index tie
    }
    if (e == 0) {
      sscore[tok] = 1.f / (1.f + __expf(-m));
      expert_id[t0 + tok] = be;
      atomicAdd(&counts[be], 1);
    }
  }
  __syncthreads();
  {
    const float sc = sscore[tid >> 5];
    const int base = (tid >> 5) * H + (tid & 31) * 32;
    #pragma unroll
    for (int i = 0; i < 4; ++i) {
      short8 vx, vs;
      #pragma unroll
      for (int j = 0; j < 8; ++j) {
        float v = xl[base + i * 8 + j];
        vx[j] = (short)f2bf(v);
        vs[j] = (short)f2bf(v * sc);
      }
      *(short8*)(xbf  + t0 * H + base + i * 8) = vx;
      *(short8*)(xsbf + t0 * H + base + i * 8) = vs;
    }
  }
}

// ---- 2) scan: offsets, cursors, tile table ------------------------------

__global__ void scan_kernel(const int* __restrict__ counts, int* __restrict__ offsets,
                            int* __restrict__ cursor, int* __restrict__ tile_e,
                            int* __restrict__ tile_p, int* __restrict__ n_tiles)
{
  if (threadIdx.x != 0) return;
  int off = 0, nt = 0;
  for (int e = 0; e < NE; ++e) {
    offsets[e] = off; cursor[e] = off;
    int cc = counts[e];
    for (int k = 0; k < cc; k += BM) { tile_e[nt] = e; tile_p[nt] = off + k; ++nt; }
    off += cc;
  }
  offsets[NE] = off;
  n_tiles[0] = nt;
}

// ---- 3) perm build -------------------------------------------------------

__global__ __launch_bounds__(256) void perm_kernel(
    const int* __restrict__ expert_id, int* __restrict__ cursor, int* __restrict__ perm)
{
  int t = blockIdx.x * 256 + threadIdx.x;
  int e = expert_id[t];
  int pos = atomicAdd(&cursor[e], 1);
  perm[pos] = t;
}

// ---- 4) fused gate+up GEMM -> act = bf16(silu(xWg) * xWu) ---------------
// BM=128 x BN=64, BK=64, 4 waves. Double-buffered 2-phase pipeline:
// issue stage(t+1) (gll16 A + W fp32->reg), MFMA(t), convert+ds_write(t+1),
// one barrier per K-step. LDS rows 128B, XOR-swizzled byte^=(row&7)<<4.

template<bool ROUTED>
__global__ __launch_bounds__(256, 2) void gateup_kernel(
    const unsigned short* __restrict__ Abase,
    const float* __restrict__ WgAll, const float* __restrict__ WuAll,
    unsigned short* __restrict__ act,
    const int* __restrict__ perm, const int* __restrict__ tile_e,
    const int* __restrict__ tile_p, const int* __restrict__ offsets,
    const int* __restrict__ n_tiles)
{
  __shared__ short Alds[2][BM * BK];   // 2x16KB
  __shared__ short Glds[2][BN * BK];   // 2x8KB
  __shared__ short Ulds[2][BN * BK];   // 2x8KB  (64KB total)

  const int tid = threadIdx.x;
  const int wave = tid >> 6, lane = tid & 63;

  int row0, row_end;
  const float *Wg, *Wu;
  if constexpr (ROUTED) {
    if ((int)blockIdx.x >= *n_tiles) return;
    const int e = tile_e[blockIdx.x];
    row0 = tile_p[blockIdx.x];
    row_end = offsets[e + 1];
    Wg = WgAll + (size_t)e * H * IDIM;
    Wu = WuAll + (size_t)e * H * IDIM;
  } else {
    row0 = blockIdx.x * BM; row_end = row0 + BM;
    Wg = WgAll; Wu = WuAll;
  }
  const int n0 = blockIdx.y * BN;

  // A staging descriptors (global src pre-swizzled; LDS dest linear, rule #21)
  const unsigned short* asrc[4];
  int aoff[4];
  #pragma unroll
  for (int i = 0; i < 4; ++i) {
    const int r = i * 32 + wave * 8 + (lane >> 3);
    int grow;
    if constexpr (ROUTED) {
      int p = row0 + r;
      if (p >= row_end) p = row0;       // clamp padded rows to a valid token
      grow = perm[p];
    } else grow = row0 + r;
    const int cb = ((lane & 7) * 16) ^ ((r & 7) << 4);
    asrc[i] = Abase + (size_t)grow * H + (cb >> 1);
    aoff[i] = (i * 32 + wave * 8) * BK;  // wave-uniform LDS row base
  }

  const int k4 = (tid & 15) * 4;   // W stage: 4x4 fp32 block per thread
  const int nj = (tid >> 4) * 4;

  f32x4 accg[2][4] = {};
  f32x4 accu[2][4] = {};
  float4v g4[4], u4[4];

  auto stageA = [&](int k0, int buf) {
    #pragma unroll
    for (int i = 0; i < 4; ++i) gll16(asrc[i] + k0, &Alds[buf][aoff[i]]);
  };
  auto loadW = [&](int k0) {
    #pragma unroll
    for (int i = 0; i < 4; ++i) {
      g4[i] = *(const float4v*)(Wg + (size_t)(k0 + k4 + i) * IDIM + (n0 + nj));
      u4[i] = *(const float4v*)(Wu + (size_t)(k0 + k4 + i) * IDIM + (n0 + nj));
    }
  };
  auto writeW = [&](int buf) {
    #pragma unroll
    for (int j = 0; j < 4; ++j) {
      const int n = nj + j;
      const int sb = (k4 * 2) ^ ((n & 7) << 4);
      uint2v pg, pu;
      pg.x = (unsigned)f2bf(g4[0][j]) | ((unsigned)f2bf(g4[1][j]) << 16);
      pg.y = (unsigned)f2bf(g4[2][j]) | ((unsigned)f2bf(g4[3][j]) << 16);
      pu.x = (unsigned)f2bf(u4[0][j]) | ((unsigned)f2bf(u4[1][j]) << 16);
      pu.y = (unsigned)f2bf(u4[2][j]) | ((unsigned)f2bf(u4[3][j]) << 16);
      *(uint2v*)((char*)Glds[buf] + n * 128 + sb) = pg;
      *(uint2v*)((char*)Ulds[buf] + n * 128 + sb) = pu;
    }
  };
  auto compute = [&](int buf) {
    #pragma unroll
    for (int kk = 0; kk < 2; ++kk) {
      short8 af[2];
      #pragma unroll
      for (int m = 0; m < 2; ++m) {
        const int r = wave * 32 + m * 16 + (lane & 15);
        const int cb = (kk * 64 + ((lane >> 4) * 16)) ^ ((r & 7) << 4);
        af[m] = *(const short8*)((const char*)Alds[buf] + r * 128 + cb);
      }
      #pragma unroll
      for (int nf = 0; nf < 4; ++nf) {
        const int n = nf * 16 + (lane & 15);
        const int cb = (kk * 64 + ((lane >> 4) * 16)) ^ ((n & 7) << 4);
        short8 bg = *(const short8*)((const char*)Glds[buf] + n * 128 + cb);
        short8 bu = *(const short8*)((const char*)Ulds[buf] + n * 128 + cb);
        #pragma unroll
        for (int m = 0; m < 2; ++m) {
          accg[m][nf] = mfma16(af[m], bg, accg[m][nf]);
          accu[m][nf] = mfma16(af[m], bu, accu[m][nf]);
        }
      }
    }
  };

  // prologue: stage tile 0
  stageA(0, 0);
  loadW(0);
  writeW(0);
  __syncthreads();

  int cur = 0;
  #pragma unroll 1
  for (int kt = 0; kt < H / BK - 1; ++kt) {
    stageA((kt + 1) * BK, cur ^ 1);   // async A(t+1), in flight across MFMA
    loadW((kt + 1) * BK);             // W(t+1) -> regs, latency hidden by MFMA
    compute(cur);
    writeW(cur ^ 1);                  // vmcnt waits for g4/u4, then ds_write
    __syncthreads();                  // drains vmcnt+lgkm; tile t+1 ready
    cur ^= 1;
  }
  compute(cur);

  // epilogue: silu(g)*u -> bf16 act
  #pragma unroll
  for (int m = 0; m < 2; ++m)
    #pragma unroll
    for (int nf = 0; nf < 4; ++nf) {
      const int col = n0 + nf * 16 + (lane & 15);
      #pragma unroll
      for (int j = 0; j < 4; ++j) {
        const int row = row0 + wave * 32 + m * 16 + ((lane >> 4) * 4) + j;
        if (ROUTED && row >= row_end) continue;
        const float g = accg[m][nf][j];
        const float u = accu[m][nf][j];
        const float v = (g / (1.f + __expf(-g))) * u;
        act[(size_t)row * IDIM + col] = f2bf(v);
      }
    }
}

// ---- 5) down GEMM: out = act @ Wd (+ scatter-add for routed) ------------

template<bool ROUTED>
__global__ __launch_bounds__(256, 2) void down_kernel(
    const unsigned short* __restrict__ act,
    const float* __restrict__ WdAll,
    float* __restrict__ out,
    const int* __restrict__ perm, const int* __restrict__ tile_e,
    const int* __restrict__ tile_p, const int* __restrict__ offsets,
    const int* __restrict__ n_tiles)
{
  __shared__ short Alds[2][BM * BK];   // 2x16KB
  __shared__ short Wlds[2][BN * BK];   // 2x8KB  (48KB total)

  const int tid = threadIdx.x;
  const int wave = tid >> 6, lane = tid & 63;

  int row0, row_end;
  const float* Wd;
  if constexpr (ROUTED) {
    if ((int)blockIdx.x >= *n_tiles) return;
    const int e = tile_e[blockIdx.x];
    row0 = tile_p[blockIdx.x];
    row_end = offsets[e + 1];
    Wd = WdAll + (size_t)e * IDIM * H;
  } else {
    row0 = blockIdx.x * BM; row_end = row0 + BM;
    Wd = WdAll;
  }
  const int n0 = blockIdx.y * BN;

  const unsigned short* asrc[4];
  int aoff[4];
  #pragma unroll
  for (int i = 0; i < 4; ++i) {
    const int r = i * 32 + wave * 8 + (lane >> 3);
    int p = row0 + r;
    if (ROUTED && p >= row_end) p = row0;
    const int cb = ((lane & 7) * 16) ^ ((r & 7) << 4);
    asrc[i] = act + (size_t)p * IDIM + (cb >> 1);
    aoff[i] = (i * 32 + wave * 8) * BK;
  }

  const int k4 = (tid & 15) * 4;
  const int nj = (tid >> 4) * 4;

  f32x4 acc[2][4] = {};
  float4v w4[4];

  auto stageA = [&](int k0, int buf) {
    #pragma unroll
    for (int i = 0; i < 4; ++i) gll16(asrc[i] + k0, &Alds[buf][aoff[i]]);
  };
  auto loadW = [&](int k0) {
    #pragma unroll
    for (int i = 0; i < 4; ++i)
      w4[i] = *(const float4v*)(Wd + (size_t)(k0 + k4 + i) * H + (n0 + nj));
  };
  auto writeW = [&](int buf) {
    #pragma unroll
    for (int j = 0; j < 4; ++j) {
      const int n = nj + j;
      const int sb = (k4 * 2) ^ ((n & 7) << 4);
      uint2v pw;
      pw.x = (unsigned)f2bf(w4[0][j]) | ((unsigned)f2bf(w4[1][j]) << 16);
      pw.y = (unsigned)f2bf(w4[2][j]) | ((unsigned)f2bf(w4[3][j]) << 16);
      *(uint2v*)((char*)Wlds[buf] + n * 128 + sb) = pw;
    }
  };
  auto compute = [&](int buf) {
    #pragma unroll
    for (int kk = 0; kk < 2; ++kk) {
      short8 af[2];
      #pragma unroll
      for (int m = 0; m < 2; ++m) {
        const int r = wave * 32 + m * 16 + (lane & 15);
        const int cb = (kk * 64 + ((lane >> 4) * 16)) ^ ((r & 7) << 4);
        af[m] = *(const short8*)((const char*)Alds[buf] + r * 128 + cb);
      }
      #pragma unroll
      for (int nf = 0; nf < 4; ++nf) {
        const int n = nf * 16 + (lane & 15);
        const int cb = (kk * 64 + ((lane >> 4) * 16)) ^ ((n & 7) << 4);
        short8 bw = *(const short8*)((const char*)Wlds[buf] + n * 128 + cb);
        #pragma unroll
        for (int m = 0; m < 2; ++m) acc[m][nf] = mfma16(af[m], bw, acc[m][nf]);
      }
    }
  };

  stageA(0, 0);
  loadW(0);
  writeW(0);
  __syncthreads();

  int cur = 0;
  #pragma unroll 1
  for (int kt = 0; kt < IDIM / BK - 1; ++kt) {
    stageA((kt + 1) * BK, cur ^ 1);
    loadW((kt + 1) * BK);
    compute(cur);
    writeW(cur ^ 1);
    __syncthreads();
    cur ^= 1;
  }
  compute(cur);

  #pragma unroll
  for (int m = 0; m < 2; ++m)
    #pragma unroll
    for (int nf = 0; nf < 4; ++nf) {
      const int col = n0 + nf * 16 + (lane & 15);
      #pragma unroll
      for (int j = 0; j < 4; ++j) {
        const int row = row0 + wave * 32 + m * 16 + ((lane >> 4) * 4) + j;
        const float v = acc[m][nf][j];
        if constexpr (ROUTED) {
          if (row < row_end) {
            const int t = perm[row];
            out[(size_t)t * H + col] += v;     // shared pass wrote first
          }
        } else {
          out[(size_t)row * H + col] = v;
        }
      }
    }
}

// ---- launch --------------------------------------------------------------

extern "C" void kernel_launch(void* const* d_in, const int* in_sizes, int n_in,
                              void* d_out, int out_size, void* d_ws, size_t ws_size,
                              hipStream_t stream) {
  (void)in_sizes; (void)n_in; (void)out_size; (void)ws_size;
  const float* x      = (const float*)d_in[0];
  const float* gate_w = (const float*)d_in[1];
  const float* sgw    = (const float*)d_in[2];
  const float* suw    = (const float*)d_in[3];
  const float* sdw    = (const float*)d_in[4];
  const float* rgw    = (const float*)d_in[5];
  const float* ruw    = (const float*)d_in[6];
  const float* rdw    = (const float*)d_in[7];
  float* out = (float*)d_out;

  char* ws = (char*)d_ws;
  unsigned short* xbf  = (unsigned short*)(ws + 0);           // 16MB
  unsigned short* xsbf = (unsigned short*)(ws + 16777216);    // 16MB
  unsigned short* act  = (unsigned short*)(ws + 33554432);    // 32MB
  int* perm      = (int*)(ws + 67108864);                     // 32KB
  int* expert_id = (int*)(ws + 67141632);                     // 32KB
  int* counts    = (int*)(ws + 67174400);
  int* offsets   = (int*)(ws + 67174528);
  int* cursor    = (int*)(ws + 67174784);
  int* tile_e    = (int*)(ws + 67174912);
  int* tile_p    = (int*)(ws + 67175424);
  int* n_tiles   = (int*)(ws + 67175936);

  hipMemsetAsync(counts, 0, NE * sizeof(int), stream);
  router_kernel<<<TOK / 8, 256, 0, stream>>>(x, gate_w, xbf, xsbf, expert_id, counts);
  scan_kernel<<<1, 64, 0, stream>>>(counts, offsets, cursor, tile_e, tile_p, n_tiles);
  perm_kernel<<<TOK / 256, 256, 0, stream>>>(expert_id, cursor, perm);

  gateup_kernel<false><<<dim3(TOK / BM, IDIM / BN), 256, 0, stream>>>(
      xbf, sgw, suw, act, perm, tile_e, tile_p, offsets, n_tiles);
  down_kernel<false><<<dim3(TOK / BM, H / BN), 256, 0, stream>>>(
      act, sdw, out, perm, tile_e, tile_p, offsets, n_tiles);
  gateup_kernel<true><<<dim3(MAX_TILES, IDIM / BN), 256, 0, stream>>>(
      xsbf, rgw, ruw, act, perm, tile_e, tile_p, offsets, n_tiles);
  down_kernel<true><<<dim3(MAX_TILES, H / BN), 256, 0, stream>>>(
      act, rdw, out, perm, tile_e, tile_p, offsets, n_tiles);
}

// Round 3
// 771.019 us; speedup vs baseline: 1.2723x; 1.2723x over previous
//
#include <hip/hip_runtime.h>
#include <stdint.h>
#include <stddef.h>

#define TOK 8192
#define H 1024
#define IDIM 2048
#define NE 32
#define BM 128
#define BN 64
#define BK 64
#define MAX_TILES 96

typedef __attribute__((ext_vector_type(8))) short short8;
typedef __attribute__((ext_vector_type(4))) float f32x4;
typedef __attribute__((ext_vector_type(4))) float float4v;
typedef __attribute__((ext_vector_type(2))) unsigned int uint2v;

// ---- helpers -------------------------------------------------------------

__device__ __forceinline__ unsigned short f2bf(float x) {   // RNE fp32->bf16
  unsigned u = __builtin_bit_cast(unsigned, x);
  u += 0x7fffu + ((u >> 16) & 1u);
  return (unsigned short)(u >> 16);
}

// async global->LDS, 16B per lane; LDS dest = wave-uniform base + lane*16
__device__ __forceinline__ void gll16(const void* g, void* l) {
  __builtin_amdgcn_global_load_lds(
      (const __attribute__((address_space(1))) unsigned int*)g,
      (__attribute__((address_space(3))) unsigned int*)l, 16, 0, 0);
}

__device__ __forceinline__ f32x4 mfma16(short8 a, short8 b, f32x4 c) {
  return __builtin_amdgcn_mfma_f32_16x16x32_bf16(a, b, c, 0, 0, 0);
}

// W-LDS swizzle: 8 distinct 16B slots for both the b64 transposed writes
// (lanes vary n by 4) and the b128 fragment reads (lanes vary n by 1).
__device__ __forceinline__ int wswz(int n) {
  return ((((n >> 2) & 7) ^ ((n & 3) << 1)) & 7) << 4;
}

// ---- 1) router: logits, top-1, sigmoid, bf16 casts ----------------------

__global__ __launch_bounds__(256) void router_kernel(
    const float* __restrict__ x, const float* __restrict__ gw,
    unsigned short* __restrict__ xbf, unsigned short* __restrict__ xsbf,
    int* __restrict__ expert_id, int* __restrict__ counts)
{
  __shared__ float xl[8 * H];          // 8 token rows, 32KB
  __shared__ float plog[8][8][NE];     // [chunk][tok][e]
  __shared__ float sscore[8];
  const int tid = threadIdx.x;
  const long t0 = (long)blockIdx.x * 8;

  const float4v* src = (const float4v*)(x + t0 * H);
  float4v* dst = (float4v*)xl;
  #pragma unroll
  for (int i = 0; i < 8; ++i) dst[tid + i * 256] = src[tid + i * 256];
  __syncthreads();

  {
    const int e = tid & 31, c = tid >> 5;
    float acc[8] = {0, 0, 0, 0, 0, 0, 0, 0};
    const float* gp = gw + (c * 128) * NE + e;
    for (int h = 0; h < 128; ++h) {
      float g = gp[h * NE];
      const float* xr = xl + (c * 128 + h);
      #pragma unroll
      for (int tk = 0; tk < 8; ++tk) acc[tk] += xr[tk * H] * g;
    }
    #pragma unroll
    for (int tk = 0; tk < 8; ++tk) plog[c][tk][e] = acc[tk];
  }
  __syncthreads();
  {
    const int e = tid & 31, tok = tid >> 5;
    float lg = 0.f;
    #pragma unroll
    for (int c = 0; c < 8; ++c) lg += plog[c][tok][e];
    float m = lg; int be = e;
    #pragma unroll
    for (int mask = 16; mask >= 1; mask >>= 1) {   // reduce within 32-lane group
      float om = __shfl_xor(m, mask);
      int   oe = __shfl_xor(be, mask);
      if (om > m || (om == m && oe < be)) { m = om; be = oe; }  // first-index tie
    }
    if (e == 0) {
      sscore[tok] = 1.f / (1.f + __expf(-m));
      expert_id[t0 + tok] = be;
      atomicAdd(&counts[be], 1);
    }
  }
  __syncthreads();
  {
    const float sc = sscore[tid >> 5];
    const int base = (tid >> 5) * H + (tid & 31) * 32;
    #pragma unroll
    for (int i = 0; i < 4; ++i) {
      short8 vx, vs;
      #pragma unroll
      for (int j = 0; j < 8; ++j) {
        float v = xl[base + i * 8 + j];
        vx[j] = (short)f2bf(v);
        vs[j] = (short)f2bf(v * sc);
      }
      *(short8*)(xbf  + t0 * H + base + i * 8) = vx;
      *(short8*)(xsbf + t0 * H + base + i * 8) = vs;
    }
  }
}

// ---- 2) scan: offsets, cursors, tile table ------------------------------

__global__ void scan_kernel(const int* __restrict__ counts, int* __restrict__ offsets,
                            int* __restrict__ cursor, int* __restrict__ tile_e,
                            int* __restrict__ tile_p, int* __restrict__ n_tiles)
{
  if (threadIdx.x != 0) return;
  int off = 0, nt = 0;
  for (int e = 0; e < NE; ++e) {
    offsets[e] = off; cursor[e] = off;
    int cc = counts[e];
    for (int k = 0; k < cc; k += BM) { tile_e[nt] = e; tile_p[nt] = off + k; ++nt; }
    off += cc;
  }
  offsets[NE] = off;
  n_tiles[0] = nt;
}

// ---- 3) perm build -------------------------------------------------------

__global__ __launch_bounds__(256) void perm_kernel(
    const int* __restrict__ expert_id, int* __restrict__ cursor, int* __restrict__ perm)
{
  int t = blockIdx.x * 256 + threadIdx.x;
  int e = expert_id[t];
  int pos = atomicAdd(&cursor[e], 1);
  perm[pos] = t;
}

// ---- 4) fused gate+up GEMM -> act = bf16(silu(xWg) * xWu) ---------------
// BM=128 x BN=64, BK=64, 4 waves, single-buffer (round-1 structure).
// W loads COALESCED: thread t loads a 4x4 fp32 block, rows k0+4*(t>>4)+r,
// cols n0+4*(t&15); per-instr a wave covers 4 full 256B row segments.
// In-register transpose -> 4x ds_write_b64 into [n][k] LDS with wswz().

template<bool ROUTED>
__global__ __launch_bounds__(256, 2) void gateup_kernel(
    const unsigned short* __restrict__ Abase,
    const float* __restrict__ WgAll, const float* __restrict__ WuAll,
    unsigned short* __restrict__ act,
    const int* __restrict__ perm, const int* __restrict__ tile_e,
    const int* __restrict__ tile_p, const int* __restrict__ offsets,
    const int* __restrict__ n_tiles)
{
  __shared__ short Alds[BM * BK];   // 16KB, [row][k] swizzled ((r&7)<<4)
  __shared__ short Glds[BN * BK];   // 8KB,  [n][k] wswz
  __shared__ short Ulds[BN * BK];   // 8KB

  const int tid = threadIdx.x;
  const int wave = tid >> 6, lane = tid & 63;

  int row0, row_end;
  const float *Wg, *Wu;
  if constexpr (ROUTED) {
    if ((int)blockIdx.x >= *n_tiles) return;
    const int e = tile_e[blockIdx.x];
    row0 = tile_p[blockIdx.x];
    row_end = offsets[e + 1];
    Wg = WgAll + (size_t)e * H * IDIM;
    Wu = WuAll + (size_t)e * H * IDIM;
  } else {
    row0 = blockIdx.x * BM; row_end = row0 + BM;
    Wg = WgAll; Wu = WuAll;
  }
  const int n0 = blockIdx.y * BN;

  // A staging (global src pre-swizzled; LDS dest linear, rule #21)
  const unsigned short* asrc[4];
  short* adst[4];
  #pragma unroll
  for (int i = 0; i < 4; ++i) {
    const int r = i * 32 + wave * 8 + (lane >> 3);
    int grow;
    if constexpr (ROUTED) {
      int p = row0 + r;
      if (p >= row_end) p = row0;
      grow = perm[p];
    } else grow = row0 + r;
    const int cb = ((lane & 7) * 16) ^ ((r & 7) << 4);
    asrc[i] = Abase + (size_t)grow * H + (cb >> 1);
    adst[i] = Alds + (i * 32 + wave * 8) * BK;
  }

  // W staging mapping
  const int wq = tid >> 4;          // 0..15 -> k row group (4 rows each)
  const int wc = tid & 15;          // 0..15 -> n quad

  f32x4 accg[2][4] = {};
  f32x4 accu[2][4] = {};

  for (int kt = 0; kt < H / BK; ++kt) {
    const int k0 = kt * BK;
    __syncthreads();                      // prev compute done
    #pragma unroll
    for (int i = 0; i < 4; ++i) gll16(asrc[i] + k0, adst[i]);

    float4v g4[4], u4[4];
    #pragma unroll
    for (int r = 0; r < 4; ++r) {
      const size_t goff = (size_t)(k0 + wq * 4 + r) * IDIM + (n0 + wc * 4);
      g4[r] = *(const float4v*)(Wg + goff);
      u4[r] = *(const float4v*)(Wu + goff);
    }
    #pragma unroll
    for (int j = 0; j < 4; ++j) {         // transpose 4x4 -> [n][k] b64 writes
      const int n = wc * 4 + j;
      const int cb = (wq * 8) ^ wswz(n);
      uint2v pg, pu;
      pg.x = (unsigned)f2bf(g4[0][j]) | ((unsigned)f2bf(g4[1][j]) << 16);
      pg.y = (unsigned)f2bf(g4[2][j]) | ((unsigned)f2bf(g4[3][j]) << 16);
      pu.x = (unsigned)f2bf(u4[0][j]) | ((unsigned)f2bf(u4[1][j]) << 16);
      pu.y = (unsigned)f2bf(u4[2][j]) | ((unsigned)f2bf(u4[3][j]) << 16);
      *(uint2v*)((char*)Glds + n * 128 + cb) = pg;
      *(uint2v*)((char*)Ulds + n * 128 + cb) = pu;
    }
    __syncthreads();                      // staging visible

    #pragma unroll
    for (int kk = 0; kk < 2; ++kk) {
      short8 af[2];
      #pragma unroll
      for (int m = 0; m < 2; ++m) {
        const int r = wave * 32 + m * 16 + (lane & 15);
        const int cb = (kk * 64 + ((lane >> 4) * 16)) ^ ((r & 7) << 4);
        af[m] = *(const short8*)((const char*)Alds + r * 128 + cb);
      }
      #pragma unroll
      for (int nf = 0; nf < 4; ++nf) {
        const int n = nf * 16 + (lane & 15);
        const int cb = (kk * 64 + ((lane >> 4) * 16)) ^ wswz(n);
        short8 bg = *(const short8*)((const char*)Glds + n * 128 + cb);
        short8 bu = *(const short8*)((const char*)Ulds + n * 128 + cb);
        #pragma unroll
        for (int m = 0; m < 2; ++m) {
          accg[m][nf] = mfma16(af[m], bg, accg[m][nf]);
          accu[m][nf] = mfma16(af[m], bu, accu[m][nf]);
        }
      }
    }
  }

  // epilogue: silu(g)*u -> bf16 act
  #pragma unroll
  for (int m = 0; m < 2; ++m)
    #pragma unroll
    for (int nf = 0; nf < 4; ++nf) {
      const int col = n0 + nf * 16 + (lane & 15);
      #pragma unroll
      for (int j = 0; j < 4; ++j) {
        const int row = row0 + wave * 32 + m * 16 + ((lane >> 4) * 4) + j;
        if (ROUTED && row >= row_end) continue;
        const float g = accg[m][nf][j];
        const float u = accu[m][nf][j];
        const float v = (g / (1.f + __expf(-g))) * u;
        act[(size_t)row * IDIM + col] = f2bf(v);
      }
    }
}

// ---- 5) down GEMM: out = act @ Wd (+ scatter-add for routed) ------------

template<bool ROUTED>
__global__ __launch_bounds__(256, 2) void down_kernel(
    const unsigned short* __restrict__ act,
    const float* __restrict__ WdAll,
    float* __restrict__ out,
    const int* __restrict__ perm, const int* __restrict__ tile_e,
    const int* __restrict__ tile_p, const int* __restrict__ offsets,
    const int* __restrict__ n_tiles)
{
  __shared__ short Alds[BM * BK];   // 16KB
  __shared__ short Wlds[BN * BK];   // 8KB

  const int tid = threadIdx.x;
  const int wave = tid >> 6, lane = tid & 63;

  int row0, row_end;
  const float* Wd;
  if constexpr (ROUTED) {
    if ((int)blockIdx.x >= *n_tiles) return;
    const int e = tile_e[blockIdx.x];
    row0 = tile_p[blockIdx.x];
    row_end = offsets[e + 1];
    Wd = WdAll + (size_t)e * IDIM * H;
  } else {
    row0 = blockIdx.x * BM; row_end = row0 + BM;
    Wd = WdAll;
  }
  const int n0 = blockIdx.y * BN;

  const unsigned short* asrc[4];
  short* adst[4];
  #pragma unroll
  for (int i = 0; i < 4; ++i) {
    const int r = i * 32 + wave * 8 + (lane >> 3);
    int p = row0 + r;
    if (ROUTED && p >= row_end) p = row0;
    const int cb = ((lane & 7) * 16) ^ ((r & 7) << 4);
    asrc[i] = act + (size_t)p * IDIM + (cb >> 1);
    adst[i] = Alds + (i * 32 + wave * 8) * BK;
  }

  const int wq = tid >> 4;
  const int wc = tid & 15;

  f32x4 acc[2][4] = {};

  for (int kt = 0; kt < IDIM / BK; ++kt) {
    const int k0 = kt * BK;
    __syncthreads();
    #pragma unroll
    for (int i = 0; i < 4; ++i) gll16(asrc[i] + k0, adst[i]);

    float4v w4[4];
    #pragma unroll
    for (int r = 0; r < 4; ++r)
      w4[r] = *(const float4v*)(Wd + (size_t)(k0 + wq * 4 + r) * H + (n0 + wc * 4));
    #pragma unroll
    for (int j = 0; j < 4; ++j) {
      const int n = wc * 4 + j;
      const int cb = (wq * 8) ^ wswz(n);
      uint2v pw;
      pw.x = (unsigned)f2bf(w4[0][j]) | ((unsigned)f2bf(w4[1][j]) << 16);
      pw.y = (unsigned)f2bf(w4[2][j]) | ((unsigned)f2bf(w4[3][j]) << 16);
      *(uint2v*)((char*)Wlds + n * 128 + cb) = pw;
    }
    __syncthreads();

    #pragma unroll
    for (int kk = 0; kk < 2; ++kk) {
      short8 af[2];
      #pragma unroll
      for (int m = 0; m < 2; ++m) {
        const int r = wave * 32 + m * 16 + (lane & 15);
        const int cb = (kk * 64 + ((lane >> 4) * 16)) ^ ((r & 7) << 4);
        af[m] = *(const short8*)((const char*)Alds + r * 128 + cb);
      }
      #pragma unroll
      for (int nf = 0; nf < 4; ++nf) {
        const int n = nf * 16 + (lane & 15);
        const int cb = (kk * 64 + ((lane >> 4) * 16)) ^ wswz(n);
        short8 bw = *(const short8*)((const char*)Wlds + n * 128 + cb);
        #pragma unroll
        for (int m = 0; m < 2; ++m) acc[m][nf] = mfma16(af[m], bw, acc[m][nf]);
      }
    }
  }

  #pragma unroll
  for (int m = 0; m < 2; ++m)
    #pragma unroll
    for (int nf = 0; nf < 4; ++nf) {
      const int col = n0 + nf * 16 + (lane & 15);
      #pragma unroll
      for (int j = 0; j < 4; ++j) {
        const int row = row0 + wave * 32 + m * 16 + ((lane >> 4) * 4) + j;
        const float v = acc[m][nf][j];
        if constexpr (ROUTED) {
          if (row < row_end) {
            const int t = perm[row];
            out[(size_t)t * H + col] += v;     // shared pass wrote first
          }
        } else {
          out[(size_t)row * H + col] = v;
        }
      }
    }
}

// ---- launch --------------------------------------------------------------

extern "C" void kernel_launch(void* const* d_in, const int* in_sizes, int n_in,
                              void* d_out, int out_size, void* d_ws, size_t ws_size,
                              hipStream_t stream) {
  (void)in_sizes; (void)n_in; (void)out_size; (void)ws_size;
  const float* x      = (const float*)d_in[0];
  const float* gate_w = (const float*)d_in[1];
  const float* sgw    = (const float*)d_in[2];
  const float* suw    = (const float*)d_in[3];
  const float* sdw    = (const float*)d_in[4];
  const float* rgw    = (const float*)d_in[5];
  const float* ruw    = (const float*)d_in[6];
  const float* rdw    = (const float*)d_in[7];
  float* out = (float*)d_out;

  char* ws = (char*)d_ws;
  unsigned short* xbf  = (unsigned short*)(ws + 0);           // 16MB
  unsigned short* xsbf = (unsigned short*)(ws + 16777216);    // 16MB
  unsigned short* act  = (unsigned short*)(ws + 33554432);    // 32MB
  int* perm      = (int*)(ws + 67108864);                     // 32KB
  int* expert_id = (int*)(ws + 67141632);                     // 32KB
  int* counts    = (int*)(ws + 67174400);
  int* offsets   = (int*)(ws + 67174528);
  int* cursor    = (int*)(ws + 67174784);
  int* tile_e    = (int*)(ws + 67174912);
  int* tile_p    = (int*)(ws + 67175424);
  int* n_tiles   = (int*)(ws + 67175936);

  hipMemsetAsync(counts, 0, NE * sizeof(int), stream);
  router_kernel<<<TOK / 8, 256, 0, stream>>>(x, gate_w, xbf, xsbf, expert_id, counts);
  scan_kernel<<<1, 64, 0, stream>>>(counts, offsets, cursor, tile_e, tile_p, n_tiles);
  perm_kernel<<<TOK / 256, 256, 0, stream>>>(expert_id, cursor, perm);

  gateup_kernel<false><<<dim3(TOK / BM, IDIM / BN), 256, 0, stream>>>(
      xbf, sgw, suw, act, perm, tile_e, tile_p, offsets, n_tiles);
  down_kernel<false><<<dim3(TOK / BM, H / BN), 256, 0, stream>>>(
      act, sdw, out, perm, tile_e, tile_p, offsets, n_tiles);
  gateup_kernel<true><<<dim3(MAX_TILES, IDIM / BN), 256, 0, stream>>>(
      xsbf, rgw, ruw, act, perm, tile_e, tile_p, offsets, n_tiles);
  down_kernel<true><<<dim3(MAX_TILES, H / BN), 256, 0, stream>>>(
      act, rdw, out, perm, tile_e, tile_p, offsets, n_tiles);
}

// Round 4
// 714.929 us; speedup vs baseline: 1.3721x; 1.0785x over previous
//
#include <hip/hip_runtime.h>
#include <stdint.h>
#include <stddef.h>

#define TOK 8192
#define H 1024
#define IDIM 2048
#define NE 32
#define BM 128
#define BN 64
#define BK 64
#define MAX_TILES 96

typedef __attribute__((ext_vector_type(8))) short short8;
typedef __attribute__((ext_vector_type(4))) float f32x4;
typedef __attribute__((ext_vector_type(4))) float float4v;
typedef __attribute__((ext_vector_type(2))) unsigned int uint2v;

// ---- helpers -------------------------------------------------------------

__device__ __forceinline__ unsigned short f2bf(float x) {   // RNE fp32->bf16
  unsigned u = __builtin_bit_cast(unsigned, x);
  u += 0x7fffu + ((u >> 16) & 1u);
  return (unsigned short)(u >> 16);
}

// async global->LDS, 16B per lane; LDS dest = wave-uniform base + lane*16
__device__ __forceinline__ void gll16(const void* g, void* l) {
  __builtin_amdgcn_global_load_lds(
      (const __attribute__((address_space(1))) unsigned int*)g,
      (__attribute__((address_space(3))) unsigned int*)l, 16, 0, 0);
}

__device__ __forceinline__ f32x4 mfma16(short8 a, short8 b, f32x4 c) {
  return __builtin_amdgcn_mfma_f32_16x16x32_bf16(a, b, c, 0, 0, 0);
}

// W-LDS slot swizzle: sigma(n) = (n ^ (n>>2)) & 7, byte offset sigma<<4.
// Bijective per-8 both for transposed b64 writes (vary wc => n bits 2..4)
// and b128 fragment reads (vary lane&15 => n bits 0..3). <=2-way everywhere.
__device__ __forceinline__ int wswz(int n) {
  return ((n ^ (n >> 2)) & 7) << 4;
}

// ---- 1) router: logits, top-1, sigmoid, bf16 casts ----------------------

__global__ __launch_bounds__(256) void router_kernel(
    const float* __restrict__ x, const float* __restrict__ gw,
    unsigned short* __restrict__ xbf, unsigned short* __restrict__ xsbf,
    int* __restrict__ expert_id, int* __restrict__ counts)
{
  __shared__ float xl[8 * H];          // 8 token rows, 32KB
  __shared__ float plog[8][8][NE];     // [chunk][tok][e]
  __shared__ float sscore[8];
  const int tid = threadIdx.x;
  const long t0 = (long)blockIdx.x * 8;

  const float4v* src = (const float4v*)(x + t0 * H);
  float4v* dst = (float4v*)xl;
  #pragma unroll
  for (int i = 0; i < 8; ++i) dst[tid + i * 256] = src[tid + i * 256];
  __syncthreads();

  {
    const int e = tid & 31, c = tid >> 5;
    float acc[8] = {0, 0, 0, 0, 0, 0, 0, 0};
    const float* gp = gw + (c * 128) * NE + e;
    for (int h = 0; h < 128; ++h) {
      float g = gp[h * NE];
      const float* xr = xl + (c * 128 + h);
      #pragma unroll
      for (int tk = 0; tk < 8; ++tk) acc[tk] += xr[tk * H] * g;
    }
    #pragma unroll
    for (int tk = 0; tk < 8; ++tk) plog[c][tk][e] = acc[tk];
  }
  __syncthreads();
  {
    const int e = tid & 31, tok = tid >> 5;
    float lg = 0.f;
    #pragma unroll
    for (int c = 0; c < 8; ++c) lg += plog[c][tok][e];
    float m = lg; int be = e;
    #pragma unroll
    for (int mask = 16; mask >= 1; mask >>= 1) {   // reduce within 32-lane group
      float om = __shfl_xor(m, mask);
      int   oe = __shfl_xor(be, mask);
      if (om > m || (om == m && oe < be)) { m = om; be = oe; }  // first-index tie
    }
    if (e == 0) {
      sscore[tok] = 1.f / (1.f + __expf(-m));
      expert_id[t0 + tok] = be;
      atomicAdd(&counts[be], 1);
    }
  }
  __syncthreads();
  {
    const float sc = sscore[tid >> 5];
    const int base = (tid >> 5) * H + (tid & 31) * 32;
    #pragma unroll
    for (int i = 0; i < 4; ++i) {
      short8 vx, vs;
      #pragma unroll
      for (int j = 0; j < 8; ++j) {
        float v = xl[base + i * 8 + j];
        vx[j] = (short)f2bf(v);
        vs[j] = (short)f2bf(v * sc);
      }
      *(short8*)(xbf  + t0 * H + base + i * 8) = vx;
      *(short8*)(xsbf + t0 * H + base + i * 8) = vs;
    }
  }
}

// ---- 2) scan: offsets, cursors, tile table ------------------------------

__global__ void scan_kernel(const int* __restrict__ counts, int* __restrict__ offsets,
                            int* __restrict__ cursor, int* __restrict__ tile_e,
                            int* __restrict__ tile_p, int* __restrict__ n_tiles)
{
  if (threadIdx.x != 0) return;
  int off = 0, nt = 0;
  for (int e = 0; e < NE; ++e) {
    offsets[e] = off; cursor[e] = off;
    int cc = counts[e];
    for (int k = 0; k < cc; k += BM) { tile_e[nt] = e; tile_p[nt] = off + k; ++nt; }
    off += cc;
  }
  offsets[NE] = off;
  n_tiles[0] = nt;
}

// ---- 3) perm build -------------------------------------------------------

__global__ __launch_bounds__(256) void perm_kernel(
    const int* __restrict__ expert_id, int* __restrict__ cursor, int* __restrict__ perm)
{
  int t = blockIdx.x * 256 + threadIdx.x;
  int e = expert_id[t];
  int pos = atomicAdd(&cursor[e], 1);
  perm[pos] = t;
}

// ---- 4) fused gate+up GEMM -> act = bf16(silu(xWg) * xWu) ---------------
// BM=128 x BN=64, BK=64, 4 waves. 2-phase pipeline (T3-min):
//   stage(t+1) = { gll16 A(t+1) -> A-dbuf, W(t+1) fp32 -> regs } issued
//   BEFORE compute(t); barrier drains; cvt+ds_write W between barriers.
// W global loads coalesced (4x4 blocks, 1KB/wave-instr). wswz swizzle.

template<bool ROUTED>
__global__ __launch_bounds__(256, 2) void gateup_kernel(
    const unsigned short* __restrict__ Abase,
    const float* __restrict__ WgAll, const float* __restrict__ WuAll,
    unsigned short* __restrict__ act,
    const int* __restrict__ perm, const int* __restrict__ tile_e,
    const int* __restrict__ tile_p, const int* __restrict__ offsets,
    const int* __restrict__ n_tiles)
{
  __shared__ short Alds[2][BM * BK];  // 2x16KB, [row][k] swizzled ((r&7)<<4)
  __shared__ short Glds[BN * BK];     // 8KB,  [n][k] wswz
  __shared__ short Ulds[BN * BK];     // 8KB   (48KB total -> 2 blocks/CU)

  const int tid = threadIdx.x;
  const int wave = tid >> 6, lane = tid & 63;

  int row0, row_end;
  const float *Wg, *Wu;
  if constexpr (ROUTED) {
    if ((int)blockIdx.x >= *n_tiles) return;
    const int e = tile_e[blockIdx.x];
    row0 = tile_p[blockIdx.x];
    row_end = offsets[e + 1];
    Wg = WgAll + (size_t)e * H * IDIM;
    Wu = WuAll + (size_t)e * H * IDIM;
  } else {
    row0 = blockIdx.x * BM; row_end = row0 + BM;
    Wg = WgAll; Wu = WuAll;
  }
  const int n0 = blockIdx.y * BN;

  // A staging (global src pre-swizzled; LDS dest linear, rule #21)
  const unsigned short* asrc[4];
  int aoff[4];
  #pragma unroll
  for (int i = 0; i < 4; ++i) {
    const int r = i * 32 + wave * 8 + (lane >> 3);
    int grow;
    if constexpr (ROUTED) {
      int p = row0 + r;
      if (p >= row_end) p = row0;
      grow = perm[p];
    } else grow = row0 + r;
    const int cb = ((lane & 7) * 16) ^ ((r & 7) << 4);
    asrc[i] = Abase + (size_t)grow * H + (cb >> 1);
    aoff[i] = (i * 32 + wave * 8) * BK;
  }

  const int wq = tid >> 4;          // k row group (4 rows each)
  const int wc = tid & 15;          // n quad

  f32x4 accg[2][4] = {};
  f32x4 accu[2][4] = {};
  float4v g4[4], u4[4];

  auto stageA = [&](int k0, int buf) {
    #pragma unroll
    for (int i = 0; i < 4; ++i) gll16(asrc[i] + k0, &Alds[buf][aoff[i]]);
  };
  auto loadW = [&](int k0) {
    #pragma unroll
    for (int r = 0; r < 4; ++r) {
      const size_t goff = (size_t)(k0 + wq * 4 + r) * IDIM + (n0 + wc * 4);
      g4[r] = *(const float4v*)(Wg + goff);
      u4[r] = *(const float4v*)(Wu + goff);
    }
  };
  auto writeW = [&]() {
    #pragma unroll
    for (int j = 0; j < 4; ++j) {       // transpose 4x4 -> [n][k] b64 writes
      const int n = wc * 4 + j;
      const int cb = (wq * 8) ^ wswz(n);
      uint2v pg, pu;
      pg.x = (unsigned)f2bf(g4[0][j]) | ((unsigned)f2bf(g4[1][j]) << 16);
      pg.y = (unsigned)f2bf(g4[2][j]) | ((unsigned)f2bf(g4[3][j]) << 16);
      pu.x = (unsigned)f2bf(u4[0][j]) | ((unsigned)f2bf(u4[1][j]) << 16);
      pu.y = (unsigned)f2bf(u4[2][j]) | ((unsigned)f2bf(u4[3][j]) << 16);
      *(uint2v*)((char*)Glds + n * 128 + cb) = pg;
      *(uint2v*)((char*)Ulds + n * 128 + cb) = pu;
    }
  };
  auto compute = [&](int buf) {
    #pragma unroll
    for (int kk = 0; kk < 2; ++kk) {
      short8 af[2];
      #pragma unroll
      for (int m = 0; m < 2; ++m) {
        const int r = wave * 32 + m * 16 + (lane & 15);
        const int cb = (kk * 64 + ((lane >> 4) * 16)) ^ ((r & 7) << 4);
        af[m] = *(const short8*)((const char*)Alds[buf] + r * 128 + cb);
      }
      #pragma unroll
      for (int nf = 0; nf < 4; ++nf) {
        const int n = nf * 16 + (lane & 15);
        const int cb = (kk * 64 + ((lane >> 4) * 16)) ^ wswz(n);
        short8 bg = *(const short8*)((const char*)Glds + n * 128 + cb);
        short8 bu = *(const short8*)((const char*)Ulds + n * 128 + cb);
        #pragma unroll
        for (int m = 0; m < 2; ++m) {
          accg[m][nf] = mfma16(af[m], bg, accg[m][nf]);
          accu[m][nf] = mfma16(af[m], bu, accu[m][nf]);
        }
      }
    }
  };

  // prologue: stage tile 0 fully
  stageA(0, 0);
  loadW(0);
  writeW();
  __syncthreads();                    // A(0) + W(0) visible

  int cur = 0;
  #pragma unroll 1
  for (int kt = 0; kt < H / BK - 1; ++kt) {
    stageA((kt + 1) * BK, cur ^ 1);   // async A(t+1) into other buf
    loadW((kt + 1) * BK);             // W(t+1) -> regs, hidden under compute
    compute(cur);
    __syncthreads();                  // compute done; loads drained
    writeW();                         // land W(t+1) in single W-LDS
    __syncthreads();                  // W(t+1) visible
    cur ^= 1;
  }
  compute(cur);

  // epilogue: silu(g)*u -> bf16 act
  #pragma unroll
  for (int m = 0; m < 2; ++m)
    #pragma unroll
    for (int nf = 0; nf < 4; ++nf) {
      const int col = n0 + nf * 16 + (lane & 15);
      #pragma unroll
      for (int j = 0; j < 4; ++j) {
        const int row = row0 + wave * 32 + m * 16 + ((lane >> 4) * 4) + j;
        if (ROUTED && row >= row_end) continue;
        const float g = accg[m][nf][j];
        const float u = accu[m][nf][j];
        const float v = (g / (1.f + __expf(-g))) * u;
        act[(size_t)row * IDIM + col] = f2bf(v);
      }
    }
}

// ---- 5) down GEMM: out = act @ Wd (+ scatter-add for routed) ------------

template<bool ROUTED>
__global__ __launch_bounds__(256, 2) void down_kernel(
    const unsigned short* __restrict__ act,
    const float* __restrict__ WdAll,
    float* __restrict__ out,
    const int* __restrict__ perm, const int* __restrict__ tile_e,
    const int* __restrict__ tile_p, const int* __restrict__ offsets,
    const int* __restrict__ n_tiles)
{
  __shared__ short Alds[2][BM * BK];  // 2x16KB
  __shared__ short Wlds[BN * BK];     // 8KB  (40KB total)

  const int tid = threadIdx.x;
  const int wave = tid >> 6, lane = tid & 63;

  int row0, row_end;
  const float* Wd;
  if constexpr (ROUTED) {
    if ((int)blockIdx.x >= *n_tiles) return;
    const int e = tile_e[blockIdx.x];
    row0 = tile_p[blockIdx.x];
    row_end = offsets[e + 1];
    Wd = WdAll + (size_t)e * IDIM * H;
  } else {
    row0 = blockIdx.x * BM; row_end = row0 + BM;
    Wd = WdAll;
  }
  const int n0 = blockIdx.y * BN;

  const unsigned short* asrc[4];
  int aoff[4];
  #pragma unroll
  for (int i = 0; i < 4; ++i) {
    const int r = i * 32 + wave * 8 + (lane >> 3);
    int p = row0 + r;
    if (ROUTED && p >= row_end) p = row0;
    const int cb = ((lane & 7) * 16) ^ ((r & 7) << 4);
    asrc[i] = act + (size_t)p * IDIM + (cb >> 1);
    aoff[i] = (i * 32 + wave * 8) * BK;
  }

  const int wq = tid >> 4;
  const int wc = tid & 15;

  f32x4 acc[2][4] = {};
  float4v w4[4];

  auto stageA = [&](int k0, int buf) {
    #pragma unroll
    for (int i = 0; i < 4; ++i) gll16(asrc[i] + k0, &Alds[buf][aoff[i]]);
  };
  auto loadW = [&](int k0) {
    #pragma unroll
    for (int r = 0; r < 4; ++r)
      w4[r] = *(const float4v*)(Wd + (size_t)(k0 + wq * 4 + r) * H + (n0 + wc * 4));
  };
  auto writeW = [&]() {
    #pragma unroll
    for (int j = 0; j < 4; ++j) {
      const int n = wc * 4 + j;
      const int cb = (wq * 8) ^ wswz(n);
      uint2v pw;
      pw.x = (unsigned)f2bf(w4[0][j]) | ((unsigned)f2bf(w4[1][j]) << 16);
      pw.y = (unsigned)f2bf(w4[2][j]) | ((unsigned)f2bf(w4[3][j]) << 16);
      *(uint2v*)((char*)Wlds + n * 128 + cb) = pw;
    }
  };
  auto compute = [&](int buf) {
    #pragma unroll
    for (int kk = 0; kk < 2; ++kk) {
      short8 af[2];
      #pragma unroll
      for (int m = 0; m < 2; ++m) {
        const int r = wave * 32 + m * 16 + (lane & 15);
        const int cb = (kk * 64 + ((lane >> 4) * 16)) ^ ((r & 7) << 4);
        af[m] = *(const short8*)((const char*)Alds[buf] + r * 128 + cb);
      }
      #pragma unroll
      for (int nf = 0; nf < 4; ++nf) {
        const int n = nf * 16 + (lane & 15);
        const int cb = (kk * 64 + ((lane >> 4) * 16)) ^ wswz(n);
        short8 bw = *(const short8*)((const char*)Wlds + n * 128 + cb);
        #pragma unroll
        for (int m = 0; m < 2; ++m) acc[m][nf] = mfma16(af[m], bw, acc[m][nf]);
      }
    }
  };

  stageA(0, 0);
  loadW(0);
  writeW();
  __syncthreads();

  int cur = 0;
  #pragma unroll 1
  for (int kt = 0; kt < IDIM / BK - 1; ++kt) {
    stageA((kt + 1) * BK, cur ^ 1);
    loadW((kt + 1) * BK);
    compute(cur);
    __syncthreads();
    writeW();
    __syncthreads();
    cur ^= 1;
  }
  compute(cur);

  #pragma unroll
  for (int m = 0; m < 2; ++m)
    #pragma unroll
    for (int nf = 0; nf < 4; ++nf) {
      const int col = n0 + nf * 16 + (lane & 15);
      #pragma unroll
      for (int j = 0; j < 4; ++j) {
        const int row = row0 + wave * 32 + m * 16 + ((lane >> 4) * 4) + j;
        const float v = acc[m][nf][j];
        if constexpr (ROUTED) {
          if (row < row_end) {
            const int t = perm[row];
            out[(size_t)t * H + col] += v;     // shared pass wrote first
          }
        } else {
          out[(size_t)row * H + col] = v;
        }
      }
    }
}

// ---- launch --------------------------------------------------------------

extern "C" void kernel_launch(void* const* d_in, const int* in_sizes, int n_in,
                              void* d_out, int out_size, void* d_ws, size_t ws_size,
                              hipStream_t stream) {
  (void)in_sizes; (void)n_in; (void)out_size; (void)ws_size;
  const float* x      = (const float*)d_in[0];
  const float* gate_w = (const float*)d_in[1];
  const float* sgw    = (const float*)d_in[2];
  const float* suw    = (const float*)d_in[3];
  const float* sdw    = (const float*)d_in[4];
  const float* rgw    = (const float*)d_in[5];
  const float* ruw    = (const float*)d_in[6];
  const float* rdw    = (const float*)d_in[7];
  float* out = (float*)d_out;

  char* ws = (char*)d_ws;
  unsigned short* xbf  = (unsigned short*)(ws + 0);           // 16MB
  unsigned short* xsbf = (unsigned short*)(ws + 16777216);    // 16MB
  unsigned short* act  = (unsigned short*)(ws + 33554432);    // 32MB
  int* perm      = (int*)(ws + 67108864);                     // 32KB
  int* expert_id = (int*)(ws + 67141632);                     // 32KB
  int* counts    = (int*)(ws + 67174400);
  int* offsets   = (int*)(ws + 67174528);
  int* cursor    = (int*)(ws + 67174784);
  int* tile_e    = (int*)(ws + 67174912);
  int* tile_p    = (int*)(ws + 67175424);
  int* n_tiles   = (int*)(ws + 67175936);

  hipMemsetAsync(counts, 0, NE * sizeof(int), stream);
  router_kernel<<<TOK / 8, 256, 0, stream>>>(x, gate_w, xbf, xsbf, expert_id, counts);
  scan_kernel<<<1, 64, 0, stream>>>(counts, offsets, cursor, tile_e, tile_p, n_tiles);
  perm_kernel<<<TOK / 256, 256, 0, stream>>>(expert_id, cursor, perm);

  gateup_kernel<false><<<dim3(TOK / BM, IDIM / BN), 256, 0, stream>>>(
      xbf, sgw, suw, act, perm, tile_e, tile_p, offsets, n_tiles);
  down_kernel<false><<<dim3(TOK / BM, H / BN), 256, 0, stream>>>(
      act, sdw, out, perm, tile_e, tile_p, offsets, n_tiles);
  gateup_kernel<true><<<dim3(MAX_TILES, IDIM / BN), 256, 0, stream>>>(
      xsbf, rgw, ruw, act, perm, tile_e, tile_p, offsets, n_tiles);
  down_kernel<true><<<dim3(MAX_TILES, H / BN), 256, 0, stream>>>(
      act, rdw, out, perm, tile_e, tile_p, offsets, n_tiles);
}

// Round 6
// 670.523 us; speedup vs baseline: 1.4630x; 1.0662x over previous
//
#include <hip/hip_runtime.h>
#include <stdint.h>
#include <stddef.h>

#define TOK 8192
#define H 1024
#define IDIM 2048
#define NE 32
#define BM 128
#define BN 64
#define BK 64
#define MAX_TILES 96

typedef __attribute__((ext_vector_type(8))) short short8;
typedef __attribute__((ext_vector_type(4))) float f32x4;
typedef __attribute__((ext_vector_type(4))) float float4v;
typedef __attribute__((ext_vector_type(2))) unsigned int uint2v;

// ---- helpers -------------------------------------------------------------

__device__ __forceinline__ unsigned short f2bf(float x) {   // RNE fp32->bf16
  unsigned u = __builtin_bit_cast(unsigned, x);
  u += 0x7fffu + ((u >> 16) & 1u);
  return (unsigned short)(u >> 16);
}

// async global->LDS, 16B per lane; LDS dest = wave-uniform base + lane*16
__device__ __forceinline__ void gll16(const void* g, void* l) {
  __builtin_amdgcn_global_load_lds(
      (const __attribute__((address_space(1))) unsigned int*)g,
      (__attribute__((address_space(3))) unsigned int*)l, 16, 0, 0);
}

__device__ __forceinline__ f32x4 mfma16(short8 a, short8 b, f32x4 c) {
  return __builtin_amdgcn_mfma_f32_16x16x32_bf16(a, b, c, 0, 0, 0);
}

// W-LDS slot swizzle: sigma(n) = (n ^ (n>>2)) & 7, byte offset sigma<<4.
__device__ __forceinline__ int wswz(int n) {
  return ((n ^ (n >> 2)) & 7) << 4;
}

#define WAIT_VM12_BAR() do { \
    asm volatile("s_waitcnt vmcnt(12)" ::: "memory"); \
    __builtin_amdgcn_s_barrier(); \
    __builtin_amdgcn_sched_barrier(0); } while (0)
#define WAIT_VM8_BAR() do { \
    asm volatile("s_waitcnt vmcnt(8)" ::: "memory"); \
    __builtin_amdgcn_s_barrier(); \
    __builtin_amdgcn_sched_barrier(0); } while (0)
#define WAIT_VM0_BAR() do { \
    asm volatile("s_waitcnt vmcnt(0)" ::: "memory"); \
    __builtin_amdgcn_s_barrier(); \
    __builtin_amdgcn_sched_barrier(0); } while (0)
#define WAIT_LGKM0() do { \
    asm volatile("s_waitcnt lgkmcnt(0)" ::: "memory"); } while (0)

// ---- 1) router: logits, top-1, sigmoid, bf16 casts ----------------------

__global__ __launch_bounds__(256) void router_kernel(
    const float* __restrict__ x, const float* __restrict__ gw,
    unsigned short* __restrict__ xbf, unsigned short* __restrict__ xsbf,
    int* __restrict__ expert_id, int* __restrict__ counts)
{
  __shared__ float xl[8 * H];          // 8 token rows, 32KB
  __shared__ float plog[8][8][NE];     // [chunk][tok][e]
  __shared__ float sscore[8];
  const int tid = threadIdx.x;
  const long t0 = (long)blockIdx.x * 8;

  const float4v* src = (const float4v*)(x + t0 * H);
  float4v* dst = (float4v*)xl;
  #pragma unroll
  for (int i = 0; i < 8; ++i) dst[tid + i * 256] = src[tid + i * 256];
  __syncthreads();

  {
    const int e = tid & 31, c = tid >> 5;
    float acc[8] = {0, 0, 0, 0, 0, 0, 0, 0};
    const float* gp = gw + (c * 128) * NE + e;
    for (int h = 0; h < 128; ++h) {
      float g = gp[h * NE];
      const float* xr = xl + (c * 128 + h);
      #pragma unroll
      for (int tk = 0; tk < 8; ++tk) acc[tk] += xr[tk * H] * g;
    }
    #pragma unroll
    for (int tk = 0; tk < 8; ++tk) plog[c][tk][e] = acc[tk];
  }
  __syncthreads();
  {
    const int e = tid & 31, tok = tid >> 5;
    float lg = 0.f;
    #pragma unroll
    for (int c = 0; c < 8; ++c) lg += plog[c][tok][e];
    float m = lg; int be = e;
    #pragma unroll
    for (int mask = 16; mask >= 1; mask >>= 1) {   // reduce within 32-lane group
      float om = __shfl_xor(m, mask);
      int   oe = __shfl_xor(be, mask);
      if (om > m || (om == m && oe < be)) { m = om; be = oe; }  // first-index tie
    }
    if (e == 0) {
      sscore[tok] = 1.f / (1.f + __expf(-m));
      expert_id[t0 + tok] = be;
      atomicAdd(&counts[be], 1);
    }
  }
  __syncthreads();
  {
    const float sc = sscore[tid >> 5];
    const int base = (tid >> 5) * H + (tid & 31) * 32;
    #pragma unroll
    for (int i = 0; i < 4; ++i) {
      short8 vx, vs;
      #pragma unroll
      for (int j = 0; j < 8; ++j) {
        float v = xl[base + i * 8 + j];
        vx[j] = (short)f2bf(v);
        vs[j] = (short)f2bf(v * sc);
      }
      *(short8*)(xbf  + t0 * H + base + i * 8) = vx;
      *(short8*)(xsbf + t0 * H + base + i * 8) = vs;
    }
  }
}

// ---- 2) scan: offsets, cursors, tile table ------------------------------

__global__ void scan_kernel(const int* __restrict__ counts, int* __restrict__ offsets,
                            int* __restrict__ cursor, int* __restrict__ tile_e,
                            int* __restrict__ tile_p, int* __restrict__ n_tiles)
{
  if (threadIdx.x != 0) return;
  int off = 0, nt = 0;
  for (int e = 0; e < NE; ++e) {
    offsets[e] = off; cursor[e] = off;
    int cc = counts[e];
    for (int k = 0; k < cc; k += BM) { tile_e[nt] = e; tile_p[nt] = off + k; ++nt; }
    off += cc;
  }
  offsets[NE] = off;
  n_tiles[0] = nt;
}

// ---- 3) perm build -------------------------------------------------------

__global__ __launch_bounds__(256) void perm_kernel(
    const int* __restrict__ expert_id, int* __restrict__ cursor, int* __restrict__ perm)
{
  int t = blockIdx.x * 256 + threadIdx.x;
  int e = expert_id[t];
  int pos = atomicAdd(&cursor[e], 1);
  perm[pos] = t;
}

// ---- 4) fused gate+up GEMM -> act = bf16(silu(xWg) * xWu) ---------------
// BM=128 x BN=64, BK=64, 4 waves. T4 pipeline: one raw s_barrier per K-step,
// counted vmcnt (never 0 in steady state). A & W double-buffered in LDS.
// Per iter t: ds_write W(t+1) [regs from t-1]; issue W(t+2)->regs; compute(t);
// lgkm(0); gll16 A(t+2) [wave stages its own read-stripe]; vmcnt(12); barrier.

template<bool ROUTED>
__global__ __launch_bounds__(256, 2) void gateup_kernel(
    const unsigned short* __restrict__ Abase,
    const float* __restrict__ WgAll, const float* __restrict__ WuAll,
    unsigned short* __restrict__ act,
    const int* __restrict__ perm, const int* __restrict__ tile_e,
    const int* __restrict__ tile_p, const int* __restrict__ offsets,
    const int* __restrict__ n_tiles)
{
  __shared__ short Alds[2][BM * BK];  // 2x16KB, [row][k], byte^=(row&7)<<4
  __shared__ short Glds[2][BN * BK];  // 2x8KB,  [n][k] wswz
  __shared__ short Ulds[2][BN * BK];  // 2x8KB   (64KB total)

  const int tid = threadIdx.x;
  const int wave = tid >> 6, lane = tid & 63;

  int row0, row_end;
  const float *Wg, *Wu;
  if constexpr (ROUTED) {
    if ((int)blockIdx.x >= *n_tiles) return;
    const int e = tile_e[blockIdx.x];
    row0 = tile_p[blockIdx.x];
    row_end = offsets[e + 1];
    Wg = WgAll + (size_t)e * H * IDIM;
    Wu = WuAll + (size_t)e * H * IDIM;
  } else {
    row0 = blockIdx.x * BM; row_end = row0 + BM;
    Wg = WgAll; Wu = WuAll;
  }
  const int n0 = blockIdx.y * BN;

  // A staging: wave w stages (and alone reads) rows [32w, 32w+32).
  const unsigned short* asrc[4];
  int aoff[4];
  #pragma unroll
  for (int i = 0; i < 4; ++i) {
    const int r = wave * 32 + i * 8 + (lane >> 3);
    int grow;
    if constexpr (ROUTED) {
      int p = row0 + r;
      if (p >= row_end) p = row0;
      grow = perm[p];
    } else grow = row0 + r;
    const int cb = ((lane & 7) * 16) ^ ((r & 7) << 4);
    asrc[i] = Abase + (size_t)grow * H + (cb >> 1);
    aoff[i] = (wave * 32 + i * 8) * BK;
  }

  const int wq = tid >> 4;          // k row group (4 rows each)
  const int wc = tid & 15;          // n quad

  f32x4 accg[2][4] = {};
  f32x4 accu[2][4] = {};
  float4v g4a[4], u4a[4], g4b[4], u4b[4];   // two named W reg sets (rule #20)

  auto stageA = [&](int kt) {               // gll16 tile kt -> Alds[kt&1]
    short* base = Alds[kt & 1];
    #pragma unroll
    for (int i = 0; i < 4; ++i) gll16(asrc[i] + kt * BK, base + aoff[i]);
  };
  auto loadW = [&](int kt, float4v (&g)[4], float4v (&u)[4]) {
    const int k0 = kt * BK;
    #pragma unroll
    for (int r = 0; r < 4; ++r) {
      const size_t goff = (size_t)(k0 + wq * 4 + r) * IDIM + (n0 + wc * 4);
      g[r] = *(const float4v*)(Wg + goff);
      u[r] = *(const float4v*)(Wu + goff);
    }
  };
  auto writeW = [&](int kt, const float4v (&g)[4], const float4v (&u)[4]) {
    char* gb = (char*)Glds[kt & 1];
    char* ub = (char*)Ulds[kt & 1];
    #pragma unroll
    for (int j = 0; j < 4; ++j) {           // transpose 4x4 -> [n][k] b64
      const int n = wc * 4 + j;
      const int cb = (wq * 8) ^ wswz(n);
      uint2v pg, pu;
      pg.x = (unsigned)f2bf(g[0][j]) | ((unsigned)f2bf(g[1][j]) << 16);
      pg.y = (unsigned)f2bf(g[2][j]) | ((unsigned)f2bf(g[3][j]) << 16);
      pu.x = (unsigned)f2bf(u[0][j]) | ((unsigned)f2bf(u[1][j]) << 16);
      pu.y = (unsigned)f2bf(u[2][j]) | ((unsigned)f2bf(u[3][j]) << 16);
      *(uint2v*)(gb + n * 128 + cb) = pg;
      *(uint2v*)(ub + n * 128 + cb) = pu;
    }
  };
  auto compute = [&](int kt) {
    const char* ab = (const char*)Alds[kt & 1];
    const char* gb = (const char*)Glds[kt & 1];
    const char* ub = (const char*)Ulds[kt & 1];
    #pragma unroll
    for (int kk = 0; kk < 2; ++kk) {
      short8 af[2];
      #pragma unroll
      for (int m = 0; m < 2; ++m) {
        const int r = wave * 32 + m * 16 + (lane & 15);
        const int cb = (kk * 64 + ((lane >> 4) * 16)) ^ ((r & 7) << 4);
        af[m] = *(const short8*)(ab + r * 128 + cb);
      }
      #pragma unroll
      for (int nf = 0; nf < 4; ++nf) {
        const int n = nf * 16 + (lane & 15);
        const int cb = (kk * 64 + ((lane >> 4) * 16)) ^ wswz(n);
        short8 bg = *(const short8*)(gb + n * 128 + cb);
        short8 bu = *(const short8*)(ub + n * 128 + cb);
        #pragma unroll
        for (int m = 0; m < 2; ++m) {
          accg[m][nf] = mfma16(af[m], bg, accg[m][nf]);
          accu[m][nf] = mfma16(af[m], bu, accu[m][nf]);
        }
      }
    }
  };

  // ---- prologue: vm queue order [W0(8), A0(4), W1(8), A1(4)] ----
  loadW(0, g4a, u4a);
  stageA(0);
  loadW(1, g4b, u4b);
  writeW(0, g4a, u4a);        // compiler waits W0 regs (vmcnt(12) auto)
  stageA(1);
  WAIT_LGKM0();               // ds_writes of W(0) done
  WAIT_VM12_BAR();            // A0 landed (W1+A1=12 stay in flight)

  // ---- main loop: NT=16, peel last two iters ----
  #pragma unroll 1
  for (int kt = 0; kt < H / BK - 2; kt += 2) {
    // even iter: consume set b (W kt+1), load set a (W kt+2)
    writeW(kt + 1, g4b, u4b);
    loadW(kt + 2, g4a, u4a);
    compute(kt);
    WAIT_LGKM0();
    stageA(kt + 2);
    WAIT_VM12_BAR();
    // odd iter: consume set a (W kt+2), load set b (W kt+3)
    writeW(kt + 2, g4a, u4a);
    loadW(kt + 3, g4b, u4b);
    compute(kt + 1);
    WAIT_LGKM0();
    stageA(kt + 3);
    WAIT_VM12_BAR();
  }
  {
    const int kt = H / BK - 2;   // even: consume set b (W NT-1), no new issues
    writeW(kt + 1, g4b, u4b);
    compute(kt);
    WAIT_LGKM0();
    WAIT_VM0_BAR();
    compute(kt + 1);
  }

  // epilogue: silu(g)*u -> bf16 act
  #pragma unroll
  for (int m = 0; m < 2; ++m)
    #pragma unroll
    for (int nf = 0; nf < 4; ++nf) {
      const int col = n0 + nf * 16 + (lane & 15);
      #pragma unroll
      for (int j = 0; j < 4; ++j) {
        const int row = row0 + wave * 32 + m * 16 + ((lane >> 4) * 4) + j;
        if (ROUTED && row >= row_end) continue;
        const float g = accg[m][nf][j];
        const float u = accu[m][nf][j];
        const float v = (g / (1.f + __expf(-g))) * u;
        act[(size_t)row * IDIM + col] = f2bf(v);
      }
    }
}

// ---- 5) down GEMM: out = act @ Wd (+ scatter-add for routed) ------------
// Same T4 pipeline; W is a single matrix (4 loads) -> steady vmcnt(8).
// NOTE: act rows are SORTED-order for routed (gateup wrote them at sorted
// positions) -> read act[row0+r] directly; perm applies ONLY to the output
// scatter. (Round-5 bug: perm applied on read.)

template<bool ROUTED>
__global__ __launch_bounds__(256, 2) void down_kernel(
    const unsigned short* __restrict__ act,
    const float* __restrict__ WdAll,
    float* __restrict__ out,
    const int* __restrict__ perm, const int* __restrict__ tile_e,
    const int* __restrict__ tile_p, const int* __restrict__ offsets,
    const int* __restrict__ n_tiles)
{
  __shared__ short Alds[2][BM * BK];  // 2x16KB
  __shared__ short Wlds[2][BN * BK];  // 2x8KB  (48KB total)

  const int tid = threadIdx.x;
  const int wave = tid >> 6, lane = tid & 63;

  int row0, row_end;
  const float* Wd;
  if constexpr (ROUTED) {
    if ((int)blockIdx.x >= *n_tiles) return;
    const int e = tile_e[blockIdx.x];
    row0 = tile_p[blockIdx.x];
    row_end = offsets[e + 1];
    Wd = WdAll + (size_t)e * IDIM * H;
  } else {
    row0 = blockIdx.x * BM; row_end = row0 + BM;
    Wd = WdAll;
  }
  const int n0 = blockIdx.y * BN;

  const unsigned short* asrc[4];
  int aoff[4];
  #pragma unroll
  for (int i = 0; i < 4; ++i) {
    const int r = wave * 32 + i * 8 + (lane >> 3);
    int p = row0 + r;
    if (ROUTED && p >= row_end) p = row0;
    const int cb = ((lane & 7) * 16) ^ ((r & 7) << 4);
    asrc[i] = act + (size_t)p * IDIM + (cb >> 1);   // sorted-order rows
    aoff[i] = (wave * 32 + i * 8) * BK;
  }

  const int wq = tid >> 4;
  const int wc = tid & 15;

  f32x4 acc[2][4] = {};
  float4v w4a[4], w4b[4];

  auto stageA = [&](int kt) {
    short* base = Alds[kt & 1];
    #pragma unroll
    for (int i = 0; i < 4; ++i) gll16(asrc[i] + kt * BK, base + aoff[i]);
  };
  auto loadW = [&](int kt, float4v (&w)[4]) {
    const int k0 = kt * BK;
    #pragma unroll
    for (int r = 0; r < 4; ++r)
      w[r] = *(const float4v*)(Wd + (size_t)(k0 + wq * 4 + r) * H + (n0 + wc * 4));
  };
  auto writeW = [&](int kt, const float4v (&w)[4]) {
    char* wb = (char*)Wlds[kt & 1];
    #pragma unroll
    for (int j = 0; j < 4; ++j) {
      const int n = wc * 4 + j;
      const int cb = (wq * 8) ^ wswz(n);
      uint2v pw;
      pw.x = (unsigned)f2bf(w[0][j]) | ((unsigned)f2bf(w[1][j]) << 16);
      pw.y = (unsigned)f2bf(w[2][j]) | ((unsigned)f2bf(w[3][j]) << 16);
      *(uint2v*)(wb + n * 128 + cb) = pw;
    }
  };
  auto compute = [&](int kt) {
    const char* ab = (const char*)Alds[kt & 1];
    const char* wb = (const char*)Wlds[kt & 1];
    #pragma unroll
    for (int kk = 0; kk < 2; ++kk) {
      short8 af[2];
      #pragma unroll
      for (int m = 0; m < 2; ++m) {
        const int r = wave * 32 + m * 16 + (lane & 15);
        const int cb = (kk * 64 + ((lane >> 4) * 16)) ^ ((r & 7) << 4);
        af[m] = *(const short8*)(ab + r * 128 + cb);
      }
      #pragma unroll
      for (int nf = 0; nf < 4; ++nf) {
        const int n = nf * 16 + (lane & 15);
        const int cb = (kk * 64 + ((lane >> 4) * 16)) ^ wswz(n);
        short8 bw = *(const short8*)(wb + n * 128 + cb);
        #pragma unroll
        for (int m = 0; m < 2; ++m) acc[m][nf] = mfma16(af[m], bw, acc[m][nf]);
      }
    }
  };

  // prologue: [W0(4), A0(4), W1(4), A1(4)]
  loadW(0, w4a);
  stageA(0);
  loadW(1, w4b);
  writeW(0, w4a);
  stageA(1);
  WAIT_LGKM0();
  WAIT_VM8_BAR();

  #pragma unroll 1
  for (int kt = 0; kt < IDIM / BK - 2; kt += 2) {
    writeW(kt + 1, w4b);
    loadW(kt + 2, w4a);
    compute(kt);
    WAIT_LGKM0();
    stageA(kt + 2);
    WAIT_VM8_BAR();
    writeW(kt + 2, w4a);
    loadW(kt + 3, w4b);
    compute(kt + 1);
    WAIT_LGKM0();
    stageA(kt + 3);
    WAIT_VM8_BAR();
  }
  {
    const int kt = IDIM / BK - 2;
    writeW(kt + 1, w4b);
    compute(kt);
    WAIT_LGKM0();
    WAIT_VM0_BAR();
    compute(kt + 1);
  }

  #pragma unroll
  for (int m = 0; m < 2; ++m)
    #pragma unroll
    for (int nf = 0; nf < 4; ++nf) {
      const int col = n0 + nf * 16 + (lane & 15);
      #pragma unroll
      for (int j = 0; j < 4; ++j) {
        const int row = row0 + wave * 32 + m * 16 + ((lane >> 4) * 4) + j;
        const float v = acc[m][nf][j];
        if constexpr (ROUTED) {
          if (row < row_end) {
            const int t = perm[row];
            out[(size_t)t * H + col] += v;     // shared pass wrote first
          }
        } else {
          out[(size_t)row * H + col] = v;
        }
      }
    }
}

// ---- launch --------------------------------------------------------------

extern "C" void kernel_launch(void* const* d_in, const int* in_sizes, int n_in,
                              void* d_out, int out_size, void* d_ws, size_t ws_size,
                              hipStream_t stream) {
  (void)in_sizes; (void)n_in; (void)out_size; (void)ws_size;
  const float* x      = (const float*)d_in[0];
  const float* gate_w = (const float*)d_in[1];
  const float* sgw    = (const float*)d_in[2];
  const float* suw    = (const float*)d_in[3];
  const float* sdw    = (const float*)d_in[4];
  const float* rgw    = (const float*)d_in[5];
  const float* ruw    = (const float*)d_in[6];
  const float* rdw    = (const float*)d_in[7];
  float* out = (float*)d_out;

  char* ws = (char*)d_ws;
  unsigned short* xbf  = (unsigned short*)(ws + 0);           // 16MB
  unsigned short* xsbf = (unsigned short*)(ws + 16777216);    // 16MB
  unsigned short* act  = (unsigned short*)(ws + 33554432);    // 32MB
  int* perm      = (int*)(ws + 67108864);                     // 32KB
  int* expert_id = (int*)(ws + 67141632);                     // 32KB
  int* counts    = (int*)(ws + 67174400);
  int* offsets   = (int*)(ws + 67174528);
  int* cursor    = (int*)(ws + 67174784);
  int* tile_e    = (int*)(ws + 67174912);
  int* tile_p    = (int*)(ws + 67175424);
  int* n_tiles   = (int*)(ws + 67175936);

  hipMemsetAsync(counts, 0, NE * sizeof(int), stream);
  router_kernel<<<TOK / 8, 256, 0, stream>>>(x, gate_w, xbf, xsbf, expert_id, counts);
  scan_kernel<<<1, 64, 0, stream>>>(counts, offsets, cursor, tile_e, tile_p, n_tiles);
  perm_kernel<<<TOK / 256, 256, 0, stream>>>(expert_id, cursor, perm);

  gateup_kernel<false><<<dim3(TOK / BM, IDIM / BN), 256, 0, stream>>>(
      xbf, sgw, suw, act, perm, tile_e, tile_p, offsets, n_tiles);
  down_kernel<false><<<dim3(TOK / BM, H / BN), 256, 0, stream>>>(
      act, sdw, out, perm, tile_e, tile_p, offsets, n_tiles);
  gateup_kernel<true><<<dim3(MAX_TILES, IDIM / BN), 256, 0, stream>>>(
      xsbf, rgw, ruw, act, perm, tile_e, tile_p, offsets, n_tiles);
  down_kernel<true><<<dim3(MAX_TILES, H / BN), 256, 0, stream>>>(
      act, rdw, out, perm, tile_e, tile_p, offsets, n_tiles);
}